// Round 11
// baseline (1489.441 us; speedup 1.0000x reference)
//
#include <hip/hip_runtime.h>
#include <hip/hip_bf16.h>

#define NN 50000
#define NE 800000

typedef __hip_bfloat16 bf16;
typedef __attribute__((ext_vector_type(8))) short bf16x8s;   // 8 bf16 = 4 VGPRs
typedef __attribute__((ext_vector_type(4))) float f32x4;

// ---- workspace layout (bytes) ----
#define OFF_E      0L            // e buffer (SORTED edge order) [NE,64] bf16 = 102.4 MB
#define OFF_AS     102400000L    // A_send [NN,64] bf16
#define OFF_ARF    108800000L    // A_rec  [NN,64] fp32 (deg-amplified -> fp32)
#define OFF_BCS    121600000L    // BC_s   [NN,128] bf16 (B_s | C_s)
#define OFF_BR     134400000L    // B_r    [NN,64] bf16
#define OFF_CRF    140800000L    // C_r    [NN,64] fp32
#define OFF_H      153600000L    // h      [NN,64] bf16
#define OFF_P      160000000L    // p      [NN,64] bf16
#define OFF_HAGGF  166400000L    // h_agg accum fp32 [NN,64]
#define OFF_PAGGF  179200000L    // p_agg accum fp32 [NN,64]
#define OFF_WFMT   192000000L    // formatted weights 307200 bf16
#define OFF_ROWPTR 192614400L    // (NN+1) int
#define OFF_COLIDX 192814404L    // NE int (sorted j -> original edge id)
#define OFF_SEG    196014404L    // NE int (rec of sorted edge j)
#define OFF_CNT    199214404L    // NN int (ends as deg)
#define OFF_EAGGF  199414404L    // segsum(e) fp32 [NN,64] = 12.8 MB

// ---- formatted-weight element offsets (bf16 elems) ----
#define FW_HE 0
#define FW_EE 8192
#define FW_PE 10240
#define FW_L0 12288
#define LSTR  73728
#define R_HMS  0        // hm rows[0:128]   (A_send: [h|p])
#define R_HMR  8192     // hm rows[128:256] (A_rec)
#define R_W3HM 16384    // (unused since R11 — hseed uses fp32 hm_W directly)
#define R_HU   20480    // hu [128,64]
#define R_EUS  28672    // eu rows[0:64]
#define R_EUR  32768    // eu rows[64:128]
#define R_CEU  36864    // [[I],[I],[eu rows 128:192]] K=192
#define R_PMS  49152    // pm rows[0:64]
#define R_PMR  53248    // pm rows[64:128]
#define R_CPM  57344    // [[I],[pm rows 128:192]] K=128
#define R_PU   65536    // pu [128,64]

#define AGG_STRIDE 72

__device__ __forceinline__ bf16x8s bfrag(const bf16* w, int c, int t, int lane) {
    return *(const bf16x8s*)(w + ((long)(c*4 + t)*64 + lane)*8);
}
__device__ __forceinline__ bf16x8s cvt8(const float* fp) {
    float4 f0 = ((const float4*)fp)[0];
    float4 f1 = ((const float4*)fp)[1];
    bf16 tmp[8];
    tmp[0]=__float2bfloat16(f0.x); tmp[1]=__float2bfloat16(f0.y);
    tmp[2]=__float2bfloat16(f0.z); tmp[3]=__float2bfloat16(f0.w);
    tmp[4]=__float2bfloat16(f1.x); tmp[5]=__float2bfloat16(f1.y);
    tmp[6]=__float2bfloat16(f1.z); tmp[7]=__float2bfloat16(f1.w);
    return *(const bf16x8s*)tmp;
}

// ======================= weight formatting =======================
__global__ __launch_bounds__(256) void wfmt_k(
    const float* __restrict__ he, const float* __restrict__ ee, const float* __restrict__ pe,
    const float* __restrict__ hm, const float* __restrict__ hu, const float* __restrict__ eu,
    const float* __restrict__ pm, const float* __restrict__ pu, bf16* __restrict__ wf)
{
    int s = blockIdx.x;
    const float* src = nullptr; int rowoff = 0, Ksrc = 0, Kpad = 0, mode = 0; long doff = 0;
    if      (s == 0) { src = he; Ksrc = 128; Kpad = 128; doff = FW_HE; }
    else if (s == 1) { src = ee; Ksrc = 16;  Kpad = 32;  doff = FW_EE; }
    else if (s == 2) { src = pe; Ksrc = 16;  Kpad = 32;  doff = FW_PE; }
    else {
        int i = (s - 3) / 10, g = (s - 3) % 10;
        long base = FW_L0 + (long)i*LSTR;
        const float* HM = hm + (long)i*320*64;
        const float* HU = hu + (long)i*128*64;
        const float* EU = eu + (long)i*192*64;
        const float* PM = pm + (long)i*192*64;
        const float* PU = pu + (long)i*128*64;
        switch (g) {
          case 0:  src=HM; rowoff=0;   Ksrc=128; Kpad=128; doff=base+R_HMS;  break;
          case 1:  src=HM; rowoff=128; Ksrc=128; Kpad=128; doff=base+R_HMR;  break;
          case 2:  src=HU; rowoff=0;   Ksrc=128; Kpad=128; doff=base+R_HU;   break;
          case 3:  src=EU; rowoff=0;   Ksrc=64;  Kpad=64;  doff=base+R_EUS;  break;
          case 4:  src=EU; rowoff=64;  Ksrc=64;  Kpad=64;  doff=base+R_EUR;  break;
          case 5:  src=EU; rowoff=128; Kpad=192; mode=3;   doff=base+R_CEU;  break;
          case 6:  src=PM; rowoff=0;   Ksrc=64;  Kpad=64;  doff=base+R_PMS;  break;
          case 7:  src=PM; rowoff=64;  Ksrc=64;  Kpad=64;  doff=base+R_PMR;  break;
          case 8:  src=PM; rowoff=128; Kpad=128; mode=2;   doff=base+R_CPM;  break;
          default: src=PU; rowoff=0;   Ksrc=128; Kpad=128; doff=base+R_PU;   break;
        }
    }
    int total = Kpad * 64;
    for (int idx = threadIdx.x; idx < total; idx += 256) {
        int j = idx & 7, l = (idx >> 3) & 63, ct = idx >> 9;
        int c = ct >> 2, t = ct & 3;
        int k = c*32 + (l >> 4)*8 + j;
        int n = t*16 + (l & 15);
        float v;
        if (mode == 2)      v = (k < 64) ? ((k == n) ? 1.f : 0.f)
                                         : src[(long)(rowoff + k - 64)*64 + n];
        else if (mode == 3) v = (k < 64) ? ((k == n) ? 1.f : 0.f)
                              : (k < 128) ? ((k - 64 == n) ? 1.f : 0.f)
                                          : src[(long)(rowoff + k - 128)*64 + n];
        else                v = (k < Ksrc) ? src[(long)(rowoff + k)*64 + n] : 0.f;
        wf[doff + idx] = __float2bfloat16(v);
    }
}

// ======================= CSR build =======================
__global__ __launch_bounds__(256) void hist_k(const int* __restrict__ rec, int* __restrict__ cnt)
{
    int e = blockIdx.x*256 + threadIdx.x;
    if (e < NE) atomicAdd(&cnt[rec[e]], 1);
}

__global__ __launch_bounds__(1024) void scan_k(const int* __restrict__ cnt, int* __restrict__ rowptr)
{
    __shared__ int sdata[1024];
    __shared__ int s_carry;
    int tid = threadIdx.x;
    if (tid == 0) { s_carry = 0; rowptr[0] = 0; }
    __syncthreads();
    for (int base = 0; base < NN; base += 1024) {
        int i = base + tid;
        int v = (i < NN) ? cnt[i] : 0;
        sdata[tid] = v;
        __syncthreads();
        for (int off = 1; off < 1024; off <<= 1) {
            int t = (tid >= off) ? sdata[tid - off] : 0;
            __syncthreads();
            sdata[tid] += t;
            __syncthreads();
        }
        int total = sdata[1023];
        if (i < NN) rowptr[i + 1] = s_carry + sdata[tid];
        __syncthreads();
        if (tid == 0) s_carry += total;
        __syncthreads();
    }
}

__global__ __launch_bounds__(256) void scatter_k(const int* __restrict__ rec,
    const int* __restrict__ rowptr, int* __restrict__ cursor,
    int* __restrict__ colidx, int* __restrict__ seg)
{
    int e = blockIdx.x*256 + threadIdx.x;
    if (e < NE) {
        int r = rec[e];
        int pos = atomicAdd(&cursor[r], 1);
        colidx[rowptr[r] + pos] = e;
        seg[rowptr[r] + pos] = r;
    }
}

// ======================= E1: gather-reduce A_send[s(j)] -> haggf ==========
__global__ __launch_bounds__(256) void e1_k(const bf16* __restrict__ As,
    const int* __restrict__ send, const int* __restrict__ gmap,
    const int* __restrict__ seg, float* __restrict__ haggf)
{
    __shared__ int s_ids[256];
    __shared__ int s_seg[256];
    int tid = threadIdx.x, lane = tid & 63, wv = tid >> 6;
    int gbase = blockIdx.x*256;
    s_ids[tid] = send[gmap[gbase + tid]];
    s_seg[tid] = seg[gbase + tid];
    __syncthreads();
    int j0 = wv*64;
    float acc = 0.f;
    int cur = s_seg[j0];
    #pragma unroll 8
    for (int jj = 0; jj < 64; ++jj) {
        int n = s_seg[j0 + jj];
        if (n != cur) { atomicAdd(&haggf[(long)cur*64 + lane], acc); acc = 0.f; cur = n; }
        acc += __bfloat162float(As[(long)s_ids[j0 + jj]*64 + lane]);
    }
    atomicAdd(&haggf[(long)cur*64 + lane], acc);
}

// ======================= hseed: haggf = eaggf @ W3hm  (pure fp32 VALU) ====
// fp32 all the way: no bf16 rounding of the deg-amplified segsum (R9 lesson).
__global__ __launch_bounds__(256) void hseed_k(const float* __restrict__ eaggf,
    const float* __restrict__ w3 /* fp32 [64][64], rows=k */, float* __restrict__ haggf)
{
    __shared__ float sw[64*64];
    int tid = threadIdx.x;
    for (int idx = tid; idx < 4096; idx += 256) sw[idx] = w3[idx];
    __syncthreads();
    int node = blockIdx.x*4 + (tid >> 6), col = tid & 63;
    if (node >= NN) return;
    const float* er = eaggf + (long)node*64;
    float s = 0.f;
    #pragma unroll 8
    for (int k = 0; k < 64; ++k) s += er[k] * sw[k*64 + col];
    haggf[(long)node*64 + col] = s;
}

// ======================= E2: e update + p_msg agg + e segsum =============
// 256 edges/block, 4 waves x 64 edges (4 M-tiles), depth-1 prefetch (eupm shape).
template <bool HASNEXT>
__global__ __launch_bounds__(256, 4) void e2_k(
    const bf16* __restrict__ BCs, const bf16* __restrict__ Br, bf16* __restrict__ e_buf,
    const int* __restrict__ send, const int* __restrict__ seg, const int* __restrict__ gmap,
    const int* __restrict__ rowptr,
    const bf16* __restrict__ wCEU, const bf16* __restrict__ wCPM,
    const float* __restrict__ eu_b,
    float* __restrict__ paggf, float* __restrict__ eaggf)
{
    __shared__ __align__(16) bf16 sE[256 * AGG_STRIDE];   // 36864 B
    int tid = threadIdx.x, lane = tid & 63, wv = tid >> 6;
    int l15 = lane & 15, q = lane >> 4;
    int row0 = blockIdx.x*256;

    int erow[4], sidx[4], ridx[4];
    #pragma unroll
    for (int et = 0; et < 4; ++et) {
        int rc = row0 + wv*64 + et*16 + l15;      // NE % 256 == 0
        erow[et] = rc;
        sidx[et] = send[gmap[rc]];
        ridx[et] = seg[rc];
    }

    // ---------- phase A: e_new = [B_s[s] | B_r[r] | e] @ CEU + eu_b ----------
    f32x4 acc[4][4];
    {
        float bv[4];
        #pragma unroll
        for (int t = 0; t < 4; ++t) bv[t] = eu_b[t*16 + l15];
        #pragma unroll
        for (int et = 0; et < 4; ++et)
            #pragma unroll
            for (int t = 0; t < 4; ++t) {
                acc[et][t][0]=bv[t]; acc[et][t][1]=bv[t]; acc[et][t][2]=bv[t]; acc[et][t][3]=bv[t];
            }
        auto loadA = [&](int c, bf16x8s* dst) {
            #pragma unroll
            for (int et = 0; et < 4; ++et) {
                if (c < 2)      dst[et] = *(const bf16x8s*)(BCs + (long)sidx[et]*128 + c*32 + q*8);
                else if (c < 4) dst[et] = *(const bf16x8s*)(Br  + (long)ridx[et]*64 + (c-2)*32 + q*8);
                else            dst[et] = *(const bf16x8s*)(e_buf + (long)erow[et]*64 + (c-4)*32 + q*8);
            }
        };
        bf16x8s af[2][4];
        loadA(0, af[0]);
        #pragma unroll
        for (int c = 0; c < 6; ++c) {
            if (c + 1 < 6) loadA(c + 1, af[(c + 1) & 1]);
            #pragma unroll
            for (int t = 0; t < 4; ++t) {
                bf16x8s bfv = bfrag(wCEU, c, t, lane);
                #pragma unroll
                for (int et = 0; et < 4; ++et)
                    acc[et][t] = __builtin_amdgcn_mfma_f32_16x16x32_bf16(af[c & 1][et], bfv, acc[et][t], 0, 0, 0);
            }
        }
    }
    // write e_new (global + LDS stride-72 tile)
    #pragma unroll
    for (int et = 0; et < 4; ++et)
        #pragma unroll
        for (int r = 0; r < 4; ++r) {
            int lr = wv*64 + et*16 + q*4 + r;
            #pragma unroll
            for (int t = 0; t < 4; ++t) {
                bf16 v = __float2bfloat16(acc[et][t][r]);
                sE[lr*AGG_STRIDE + t*16 + l15] = v;
                e_buf[(long)(row0 + lr)*64 + t*16 + l15] = v;
            }
        }
    __syncthreads();

    // ---------- phase B: p_t = [C_s[s] | e_new] @ CPM (bias handled in nup) --
    f32x4 accP[4][4];
    {
        #pragma unroll
        for (int et = 0; et < 4; ++et)
            #pragma unroll
            for (int t = 0; t < 4; ++t) {
                accP[et][t][0]=0; accP[et][t][1]=0; accP[et][t][2]=0; accP[et][t][3]=0;
            }
        auto loadB = [&](int c, bf16x8s* dst) {
            #pragma unroll
            for (int et = 0; et < 4; ++et) {
                if (c < 2) dst[et] = *(const bf16x8s*)(BCs + (long)sidx[et]*128 + 64 + c*32 + q*8);
                else       dst[et] = *(const bf16x8s*)(sE + (wv*64 + et*16 + l15)*AGG_STRIDE + (c-2)*32 + q*8);
            }
        };
        bf16x8s af[2][4];
        loadB(0, af[0]);
        #pragma unroll
        for (int c = 0; c < 4; ++c) {
            if (c + 1 < 4) loadB(c + 1, af[(c + 1) & 1]);
            #pragma unroll
            for (int t = 0; t < 4; ++t) {
                bf16x8s bfv = bfrag(wCPM, c, t, lane);
                #pragma unroll
                for (int et = 0; et < 4; ++et)
                    accP[et][t] = __builtin_amdgcn_mfma_f32_16x16x32_bf16(af[c & 1][et], bfv, accP[et][t], 0, 0, 0);
            }
        }
    }

    int col = tid & 63, wpart = tid >> 6;
    int n0 = seg[row0], n1 = seg[row0 + 255];

    // segsum(e_new) -> eaggf  (next layer's h_msg e-term; sE still holds e_new)
    if (HASNEXT) {
        for (int n = n0 + wpart; n <= n1; n += 4) {
            int beg = rowptr[n], end = rowptr[n + 1];
            if (beg < row0) beg = row0;
            if (end > row0 + 256) end = row0 + 256;
            if (beg < end) {
                float s = 0.f;
                for (int j = beg; j < end; ++j) s += __bfloat162float(sE[(j - row0)*AGG_STRIDE + col]);
                atomicAdd(&eaggf[(long)n*64 + col], s);
            }
        }
    }
    __syncthreads();   // all sE reads done

    // stage p_t, segment-sum -> paggf
    #pragma unroll
    for (int et = 0; et < 4; ++et)
        #pragma unroll
        for (int r = 0; r < 4; ++r)
            #pragma unroll
            for (int t = 0; t < 4; ++t)
                sE[(wv*64 + et*16 + q*4 + r)*AGG_STRIDE + t*16 + l15] = __float2bfloat16(accP[et][t][r]);
    __syncthreads();
    for (int n = n0 + wpart; n <= n1; n += 4) {
        int beg = rowptr[n], end = rowptr[n + 1];
        if (beg < row0) beg = row0;
        if (end > row0 + 256) end = row0 + 256;
        if (beg < end) {
            float s = 0.f;
            for (int j = beg; j < end; ++j) s += __bfloat162float(sE[(j - row0)*AGG_STRIDE + col]);
            atomicAdd(&paggf[(long)n*64 + col], s);
        }
    }
}

// ======================= eemb: e0 embed + segsum(e0) -> eaggf ============
__global__ __launch_bounds__(256) void eemb_k(
    const float* __restrict__ e_in, const int* __restrict__ gmap,
    const int* __restrict__ seg, const int* __restrict__ rowptr,
    const bf16* __restrict__ wEE, const float* __restrict__ ee_b,
    float* __restrict__ eaggf, bf16* __restrict__ e_buf)
{
    __shared__ __align__(16) bf16 sE[256 * AGG_STRIDE];
    int tid = threadIdx.x, lane = tid & 63, wv = tid >> 6;
    int l15 = lane & 15, q = lane >> 4;
    int row0 = blockIdx.x*256;

    int em[4];
    #pragma unroll
    for (int et = 0; et < 4; ++et) em[et] = gmap[row0 + wv*64 + et*16 + l15];

    f32x4 acc[4][4];
    float bv[4];
    #pragma unroll
    for (int t = 0; t < 4; ++t) bv[t] = ee_b[t*16 + l15];
    #pragma unroll
    for (int et = 0; et < 4; ++et)
        #pragma unroll
        for (int t = 0; t < 4; ++t) {
            acc[et][t][0]=bv[t]; acc[et][t][1]=bv[t]; acc[et][t][2]=bv[t]; acc[et][t][3]=bv[t];
        }
    {   // K=32 (rows 0..15 real, padded)
        bf16x8s af[4];
        #pragma unroll
        for (int et = 0; et < 4; ++et) {
            bf16x8s v = {0,0,0,0,0,0,0,0};
            if (q < 2) v = cvt8(e_in + (long)em[et]*16 + q*8);
            af[et] = v;
        }
        #pragma unroll
        for (int t = 0; t < 4; ++t) {
            bf16x8s bfv = bfrag(wEE, 0, t, lane);
            #pragma unroll
            for (int et = 0; et < 4; ++et)
                acc[et][t] = __builtin_amdgcn_mfma_f32_16x16x32_bf16(af[et], bfv, acc[et][t], 0, 0, 0);
        }
    }
    #pragma unroll
    for (int et = 0; et < 4; ++et)
        #pragma unroll
        for (int r = 0; r < 4; ++r) {
            int lr = wv*64 + et*16 + q*4 + r;
            #pragma unroll
            for (int t = 0; t < 4; ++t) {
                bf16 v = __float2bfloat16(acc[et][t][r]);
                sE[lr*AGG_STRIDE + t*16 + l15] = v;
                e_buf[(long)(row0 + lr)*64 + t*16 + l15] = v;
            }
        }
    __syncthreads();
    int col = tid & 63, wpart = tid >> 6;
    int n0 = seg[row0], n1 = seg[row0 + 255];
    for (int n = n0 + wpart; n <= n1; n += 4) {
        int beg = rowptr[n], end = rowptr[n + 1];
        if (beg < row0) beg = row0;
        if (end > row0 + 256) end = row0 + 256;
        if (beg < end) {
            float s = 0.f;
            for (int j = beg; j < end; ++j) s += __bfloat162float(sE[(j - row0)*AGG_STRIDE + col]);
            atomicAdd(&eaggf[(long)n*64 + col], s);
        }
    }
}

// ======================= node kernels (64 rows/block, 16 rows/wave) ======
__global__ __launch_bounds__(256) void hemb_k(const float* __restrict__ h_in,
    const bf16* __restrict__ wHE, const float* __restrict__ he_b, bf16* __restrict__ h)
{
    int tid = threadIdx.x, lane = tid & 63, wv = tid >> 6;
    int l15 = lane & 15, q = lane >> 4;
    int row = blockIdx.x*64 + wv*16 + l15;
    int rc = (row < NN) ? row : NN - 1;
    f32x4 acc[4];
    #pragma unroll
    for (int t = 0; t < 4; ++t) { float b = he_b[t*16 + l15]; acc[t][0]=b; acc[t][1]=b; acc[t][2]=b; acc[t][3]=b; }
    #pragma unroll
    for (int c = 0; c < 4; ++c) {
        bf16x8s af = cvt8(h_in + (long)rc*128 + c*32 + q*8);
        #pragma unroll
        for (int t = 0; t < 4; ++t)
            acc[t] = __builtin_amdgcn_mfma_f32_16x16x32_bf16(af, bfrag(wHE, c, t, lane), acc[t], 0, 0, 0);
    }
    #pragma unroll
    for (int r = 0; r < 4; ++r) {
        int ro = blockIdx.x*64 + wv*16 + q*4 + r;
        if (ro < NN)
            #pragma unroll
            for (int t = 0; t < 4; ++t) h[(long)ro*64 + t*16 + l15] = __float2bfloat16(acc[t][r]);
    }
}

__global__ __launch_bounds__(256) void pemb_k(const float* __restrict__ p_in,
    const bf16* __restrict__ wPE, const float* __restrict__ pe_b, bf16* __restrict__ p)
{
    int tid = threadIdx.x, lane = tid & 63, wv = tid >> 6;
    int l15 = lane & 15, q = lane >> 4;
    int row = blockIdx.x*64 + wv*16 + l15;
    int rc = (row < NN) ? row : NN - 1;
    f32x4 acc[4];
    #pragma unroll
    for (int t = 0; t < 4; ++t) { float b = pe_b[t*16 + l15]; acc[t][0]=b; acc[t][1]=b; acc[t][2]=b; acc[t][3]=b; }
    {
        bf16x8s af = {0,0,0,0,0,0,0,0};
        if (q < 2) af = cvt8(p_in + (long)rc*16 + q*8);
        #pragma unroll
        for (int t = 0; t < 4; ++t)
            acc[t] = __builtin_amdgcn_mfma_f32_16x16x32_bf16(af, bfrag(wPE, 0, t, lane), acc[t], 0, 0, 0);
    }
    #pragma unroll
    for (int r = 0; r < 4; ++r) {
        int ro = blockIdx.x*64 + wv*16 + q*4 + r;
        if (ro < NN)
            #pragma unroll
            for (int t = 0; t < 4; ++t) p[(long)ro*64 + t*16 + l15] = __float2bfloat16(acc[t][r]);
    }
}

// N1: A_send (bf16), A_rec (fp32); C_s (bf16 -> BCs upper), C_r (fp32)
__global__ __launch_bounds__(256) void n1_k(const bf16* __restrict__ h, const bf16* __restrict__ p,
    const bf16* __restrict__ wHMs, const bf16* __restrict__ wHMr,
    const bf16* __restrict__ wPMs, const bf16* __restrict__ wPMr,
    bf16* __restrict__ As, float* __restrict__ Arf, bf16* __restrict__ BCs, float* __restrict__ Crf)
{
    int tid = threadIdx.x, lane = tid & 63, wv = tid >> 6;
    int l15 = lane & 15, q = lane >> 4;
    int row = blockIdx.x*64 + wv*16 + l15;
    int rc = (row < NN) ? row : NN - 1;
    f32x4 aAs[4], aAr[4], aCs[4], aCr[4];
    #pragma unroll
    for (int t = 0; t < 4; ++t) {
        aAs[t][0]=0;aAs[t][1]=0;aAs[t][2]=0;aAs[t][3]=0;
        aAr[t][0]=0;aAr[t][1]=0;aAr[t][2]=0;aAr[t][3]=0;
        aCs[t][0]=0;aCs[t][1]=0;aCs[t][2]=0;aCs[t][3]=0;
        aCr[t][0]=0;aCr[t][1]=0;aCr[t][2]=0;aCr[t][3]=0;
    }
    #pragma unroll
    for (int c = 0; c < 4; ++c) {
        bf16x8s af = (c < 2) ? *(const bf16x8s*)(h + (long)rc*64 + c*32 + q*8)
                             : *(const bf16x8s*)(p + (long)rc*64 + (c-2)*32 + q*8);
        #pragma unroll
        for (int t = 0; t < 4; ++t) {
            aAs[t] = __builtin_amdgcn_mfma_f32_16x16x32_bf16(af, bfrag(wHMs, c, t, lane), aAs[t], 0, 0, 0);
            aAr[t] = __builtin_amdgcn_mfma_f32_16x16x32_bf16(af, bfrag(wHMr, c, t, lane), aAr[t], 0, 0, 0);
        }
        if (c >= 2) {
            #pragma unroll
            for (int t = 0; t < 4; ++t) {
                aCs[t] = __builtin_amdgcn_mfma_f32_16x16x32_bf16(af, bfrag(wPMs, c-2, t, lane), aCs[t], 0, 0, 0);
                aCr[t] = __builtin_amdgcn_mfma_f32_16x16x32_bf16(af, bfrag(wPMr, c-2, t, lane), aCr[t], 0, 0, 0);
            }
        }
    }
    #pragma unroll
    for (int r = 0; r < 4; ++r) {
        int ro = blockIdx.x*64 + wv*16 + q*4 + r;
        if (ro < NN) {
            #pragma unroll
            for (int t = 0; t < 4; ++t) {
                int col = t*16 + l15;
                As[(long)ro*64 + col]        = __float2bfloat16(aAs[t][r]);
                Arf[(long)ro*64 + col]       = aAr[t][r];
                BCs[(long)ro*128 + 64 + col] = __float2bfloat16(aCs[t][r]);
                Crf[(long)ro*64 + col]       = aCr[t][r];
            }
        }
    }
}

// N3: B_s (-> BCs lower half), B_r  (from h_new, K=64)
__global__ __launch_bounds__(256) void n3_k(const bf16* __restrict__ h,
    const bf16* __restrict__ wEUs, const bf16* __restrict__ wEUr,
    bf16* __restrict__ BCs, bf16* __restrict__ Br)
{
    int tid = threadIdx.x, lane = tid & 63, wv = tid >> 6;
    int l15 = lane & 15, q = lane >> 4;
    int row = blockIdx.x*64 + wv*16 + l15;
    int rc = (row < NN) ? row : NN - 1;
    f32x4 aBs[4], aBr[4];
    #pragma unroll
    for (int t = 0; t < 4; ++t) {
        aBs[t][0]=0;aBs[t][1]=0;aBs[t][2]=0;aBs[t][3]=0;
        aBr[t][0]=0;aBr[t][1]=0;aBr[t][2]=0;aBr[t][3]=0;
    }
    #pragma unroll
    for (int c = 0; c < 2; ++c) {
        bf16x8s af = *(const bf16x8s*)(h + (long)rc*64 + c*32 + q*8);
        #pragma unroll
        for (int t = 0; t < 4; ++t) {
            aBs[t] = __builtin_amdgcn_mfma_f32_16x16x32_bf16(af, bfrag(wEUs, c, t, lane), aBs[t], 0, 0, 0);
            aBr[t] = __builtin_amdgcn_mfma_f32_16x16x32_bf16(af, bfrag(wEUr, c, t, lane), aBr[t], 0, 0, 0);
        }
    }
    #pragma unroll
    for (int r = 0; r < 4; ++r) {
        int ro = blockIdx.x*64 + wv*16 + q*4 + r;
        if (ro < NN) {
            #pragma unroll
            for (int t = 0; t < 4; ++t) {
                int col = t*16 + l15;
                BCs[(long)ro*128 + col] = __float2bfloat16(aBs[t][r]);
                Br[(long)ro*64 + col]   = __float2bfloat16(aBr[t][r]);
            }
        }
    }
}

// N2/N4: x_new = [x | aggf + deg*(Rf + mb)] @ W + b
__global__ __launch_bounds__(256) void nup_k(const bf16* __restrict__ x,
    const float* __restrict__ aggf, const float* __restrict__ Rf, const int* __restrict__ deg,
    const float* __restrict__ mb, const bf16* __restrict__ wU, const float* __restrict__ ub,
    bf16* __restrict__ x_out, float* __restrict__ out2)
{
    int tid = threadIdx.x, lane = tid & 63, wv = tid >> 6;
    int l15 = lane & 15, q = lane >> 4;
    int row = blockIdx.x*64 + wv*16 + l15;
    int rc = (row < NN) ? row : NN - 1;
    float degf = (float)deg[rc];
    f32x4 acc[4];
    #pragma unroll
    for (int t = 0; t < 4; ++t) { float b = ub[t*16 + l15]; acc[t][0]=b; acc[t][1]=b; acc[t][2]=b; acc[t][3]=b; }
    #pragma unroll
    for (int c = 0; c < 4; ++c) {
        bf16x8s af;
        if (c < 2) {
            af = *(const bf16x8s*)(x + (long)rc*64 + c*32 + q*8);
        } else {
            int ch0 = (c-2)*32 + q*8;
            const float* ag = aggf + (long)rc*64 + ch0;
            const float* rr = Rf + (long)rc*64 + ch0;
            const float* bb = mb + ch0;
            bf16 tmp[8];
            #pragma unroll
            for (int u = 0; u < 8; ++u)
                tmp[u] = __float2bfloat16(ag[u] + degf*(rr[u] + bb[u]));
            af = *(const bf16x8s*)tmp;
        }
        #pragma unroll
        for (int t = 0; t < 4; ++t)
            acc[t] = __builtin_amdgcn_mfma_f32_16x16x32_bf16(af, bfrag(wU, c, t, lane), acc[t], 0, 0, 0);
    }
    #pragma unroll
    for (int r = 0; r < 4; ++r) {
        int ro = blockIdx.x*64 + wv*16 + q*4 + r;
        if (ro < NN) {
            #pragma unroll
            for (int t = 0; t < 4; ++t) {
                float fv = acc[t][r];
                x_out[(long)ro*64 + t*16 + l15] = __float2bfloat16(fv);
                if (out2) out2[(long)ro*64 + t*16 + l15] = fv;
            }
        }
    }
}

// ======================= launch =======================
extern "C" void kernel_launch(void* const* d_in, const int* in_sizes, int n_in,
                              void* d_out, int out_size, void* d_ws, size_t ws_size,
                              hipStream_t stream)
{
    (void)in_sizes; (void)n_in; (void)out_size; (void)ws_size;
    const float* h_in = (const float*)d_in[0];
    const float* e_in = (const float*)d_in[1];
    const float* p_in = (const float*)d_in[2];
    const int*  ei   = (const int*)d_in[3];
    const int* send = ei;
    const int* rec  = ei + NE;
    const float* he_W = (const float*)d_in[4];  const float* he_b = (const float*)d_in[5];
    const float* ee_W = (const float*)d_in[6];  const float* ee_b = (const float*)d_in[7];
    const float* pe_W = (const float*)d_in[8];  const float* pe_b = (const float*)d_in[9];
    const float* hm_W = (const float*)d_in[10]; const float* hm_b = (const float*)d_in[11];
    const float* hu_W = (const float*)d_in[12]; const float* hu_b = (const float*)d_in[13];
    const float* eu_W = (const float*)d_in[14]; const float* eu_b = (const float*)d_in[15];
    const float* pm_W = (const float*)d_in[16]; const float* pm_b = (const float*)d_in[17];
    const float* pu_W = (const float*)d_in[18]; const float* pu_b = (const float*)d_in[19];

    char* ws = (char*)d_ws;
    bf16* e_buf = (bf16*)(ws + OFF_E);
    bf16* As    = (bf16*)(ws + OFF_AS);
    float* Arf  = (float*)(ws + OFF_ARF);
    bf16* BCs   = (bf16*)(ws + OFF_BCS);
    bf16* Br    = (bf16*)(ws + OFF_BR);
    float* Crf  = (float*)(ws + OFF_CRF);
    bf16* h     = (bf16*)(ws + OFF_H);
    bf16* p     = (bf16*)(ws + OFF_P);
    float* haggf= (float*)(ws + OFF_HAGGF);
    float* paggf= (float*)(ws + OFF_PAGGF);
    bf16* wf    = (bf16*)(ws + OFF_WFMT);
    int* rowptr = (int*)(ws + OFF_ROWPTR);
    int* colidx = (int*)(ws + OFF_COLIDX);
    int* segarr = (int*)(ws + OFF_SEG);
    int* cnt    = (int*)(ws + OFF_CNT);
    float* eaggf= (float*)(ws + OFF_EAGGF);
    float* dout = (float*)d_out;

    const int EB  = NE / 256;           // 3125
    const int NB64 = (NN + 63) / 64;    // 782
    const int NB4  = (NN + 3) / 4;      // 12500

    // CSR build; cnt ends as deg
    (void)hipMemsetAsync(cnt, 0, NN * sizeof(int), stream);
    hist_k<<<EB, 256, 0, stream>>>(rec, cnt);
    scan_k<<<1, 1024, 0, stream>>>(cnt, rowptr);
    (void)hipMemsetAsync(cnt, 0, NN * sizeof(int), stream);
    scatter_k<<<EB, 256, 0, stream>>>(rec, rowptr, cnt, colidx, segarr);

    wfmt_k<<<43, 256, 0, stream>>>(he_W, ee_W, pe_W, hm_W, hu_W, eu_W, pm_W, pu_W, wf);

    (void)hipMemsetAsync(eaggf, 0, (long)NN*64*sizeof(float), stream);

    // embeddings
    hemb_k<<<NB64, 256, 0, stream>>>(h_in, wf + FW_HE, he_b, h);
    pemb_k<<<NB64, 256, 0, stream>>>(p_in, wf + FW_PE, pe_b, p);
    eemb_k<<<EB, 256, 0, stream>>>(e_in, colidx, segarr, rowptr,
        wf + FW_EE, ee_b, eaggf, e_buf);

    for (int i = 0; i < 4; ++i) {
        long base = FW_L0 + (long)i*LSTR;
        const float* w3hm = hm_W + (long)i*320*64 + 256*64;   // fp32 rows 256:320
        // seed: haggf = eaggf @ W3hm (fp32)
        hseed_k<<<NB4, 256, 0, stream>>>(eaggf, w3hm, haggf);
        // N1 tables
        n1_k<<<NB64, 256, 0, stream>>>(h, p,
            wf + base + R_HMS, wf + base + R_HMR, wf + base + R_PMS, wf + base + R_PMR,
            As, Arf, BCs, Crf);
        // E1: haggf += segsum(A_send[s])
        e1_k<<<EB, 256, 0, stream>>>(As, send, colidx, segarr, haggf);
        // N2: h_new
        nup_k<<<NB64, 256, 0, stream>>>(h, haggf, Arf, cnt, hm_b + i*64,
            wf + base + R_HU, hu_b + i*64, h, (i == 3) ? dout : nullptr);
        // N3: B_s, B_r from h_new
        n3_k<<<NB64, 256, 0, stream>>>(h, wf + base + R_EUS, wf + base + R_EUR, BCs, Br);
        // E2
        if (i < 3) (void)hipMemsetAsync(eaggf, 0, (long)NN*64*sizeof(float), stream);
        (void)hipMemsetAsync(paggf, 0, (long)NN*64*sizeof(float), stream);
        if (i < 3) {
            e2_k<true><<<EB, 256, 0, stream>>>(BCs, Br, e_buf, send, segarr, colidx, rowptr,
                wf + base + R_CEU, wf + base + R_CPM, eu_b + i*64, paggf, eaggf);
        } else {
            e2_k<false><<<EB, 256, 0, stream>>>(BCs, Br, e_buf, send, segarr, colidx, rowptr,
                wf + base + R_CEU, wf + base + R_CPM, eu_b + i*64, paggf, eaggf);
        }
        // N4: p_new
        nup_k<<<NB64, 256, 0, stream>>>(p, paggf, Crf, cnt, pm_b + i*64,
            wf + base + R_PU, pu_b + i*64, p, (i == 3) ? dout + (long)NN*64 : nullptr);
    }
}